// Round 2
// baseline (338.826 us; speedup 1.0000x reference)
//
#include <hip/hip_runtime.h>

#define BEV_H 512
#define BEV_W 512
#define CCH   64
#define HW    (BEV_H * BEV_W)        // 262144
#define CHW   (CCH * HW)             // 16777216 floats per batch

// ---------------------------------------------------------------- kernel 1
// Set the "winner index" slots (channel-0 plane of each batch, viewed as int)
// to -1. One thread per int4.
__global__ void bev_fill_neg1(int* __restrict__ out_i, int B) {
    int t = blockIdx.x * blockDim.x + threadIdx.x;
    const int per_b4 = HW / 4;                 // int4s per batch plane
    if (t >= B * per_b4) return;
    int b  = t / per_b4;
    int i4 = t - b * per_b4;
    int4* p = reinterpret_cast<int4*>(out_i + (size_t)b * CHW);
    p[i4] = make_int4(-1, -1, -1, -1);
}

// ---------------------------------------------------------------- kernel 2
// atomicMax scatter of pillar indices into the winner slots.
__global__ void bev_scatter_max(const int* __restrict__ coords,
                                int* __restrict__ out_i, int P) {
    int p = blockIdx.x * blockDim.x + threadIdx.x;
    if (p >= P) return;
    int b = coords[p * 3 + 0];
    int r = coords[p * 3 + 1];
    int c = coords[p * 3 + 2];
    r = min(max(r, 0), BEV_H - 1);
    c = min(max(c, 0), BEV_W - 1);
    size_t key = (size_t)b * CHW + (size_t)r * BEV_W + c;
    atomicMax(&out_i[key], p);   // device-scope by default on CDNA
}

// ---------------------------------------------------------------- kernel 3
// One thread per 4 consecutive cells along W. Reads its 4 winner indices
// (int4) from the ch-0 plane, THEN overwrites all 64 channels (float4
// stores, coalesced). Stores data-depend on the winner load, and no other
// thread touches these cells, so read-before-overwrite is safe.
__global__ void bev_gather(const float* __restrict__ feats,
                           float* __restrict__ out, int ncell4) {
    int t = blockIdx.x * blockDim.x + threadIdx.x;
    if (t >= ncell4) return;

    const int W4 = BEV_W / 4;
    int c4 = t % W4;          // group of 4 columns
    int br = t / W4;          // b*H + r
    int r  = br % BEV_H;
    int b  = br / BEV_H;

    size_t base = (size_t)b * CHW + (size_t)r * BEV_W + (size_t)c4 * 4;
    const int4 l4 = *reinterpret_cast<const int4*>(
        reinterpret_cast<const int*>(out) + base);

    const float* f0 = (l4.x >= 0) ? feats + (size_t)l4.x * CCH : nullptr;
    const float* f1 = (l4.y >= 0) ? feats + (size_t)l4.y * CCH : nullptr;
    const float* f2 = (l4.z >= 0) ? feats + (size_t)l4.z * CCH : nullptr;
    const float* f3 = (l4.w >= 0) ? feats + (size_t)l4.w * CCH : nullptr;

    float* outp = out + base;
    const float4 zero = make_float4(0.f, 0.f, 0.f, 0.f);

#pragma unroll
    for (int g = 0; g < CCH / 4; ++g) {       // 16 channel-groups of 4
        float4 a = f0 ? *reinterpret_cast<const float4*>(f0 + g * 4) : zero;
        float4 bb = f1 ? *reinterpret_cast<const float4*>(f1 + g * 4) : zero;
        float4 cc = f2 ? *reinterpret_cast<const float4*>(f2 + g * 4) : zero;
        float4 dd = f3 ? *reinterpret_cast<const float4*>(f3 + g * 4) : zero;

        // 4x4 transpose: channel ch = g*4+j gets {a[j], bb[j], cc[j], dd[j]}
        float4 v0 = make_float4(a.x, bb.x, cc.x, dd.x);
        float4 v1 = make_float4(a.y, bb.y, cc.y, dd.y);
        float4 v2 = make_float4(a.z, bb.z, cc.z, dd.z);
        float4 v3 = make_float4(a.w, bb.w, cc.w, dd.w);

        float* o = outp + (size_t)(g * 4) * HW;
        *reinterpret_cast<float4*>(o)              = v0;
        *reinterpret_cast<float4*>(o + (size_t)HW) = v1;
        *reinterpret_cast<float4*>(o + 2*(size_t)HW) = v2;
        *reinterpret_cast<float4*>(o + 3*(size_t)HW) = v3;
    }
}

// ---------------------------------------------------------------- launcher
extern "C" void kernel_launch(void* const* d_in, const int* in_sizes, int n_in,
                              void* d_out, int out_size, void* d_ws, size_t ws_size,
                              hipStream_t stream) {
    const float* feats  = (const float*)d_in[0];
    const int*   coords = (const int*)d_in[1];

    const int P = in_sizes[0] / CCH;           // 200000
    const int B = out_size / CHW;              // 4
    const int ncell  = B * HW;                 // 1,048,576
    const int ncell4 = ncell / 4;

    float* out  = (float*)d_out;
    int*   outi = (int*)d_out;

    // 1) winner slots = -1 (in the ch-0 plane of each batch)
    {
        int n = ncell4;
        int threads = 256;
        int blocks = (n + threads - 1) / threads;
        bev_fill_neg1<<<blocks, threads, 0, stream>>>(outi, B);
    }
    // 2) atomicMax scatter of pillar indices
    {
        int threads = 256;
        int blocks = (P + threads - 1) / threads;
        bev_scatter_max<<<blocks, threads, 0, stream>>>(coords, outi, P);
    }
    // 3) gather + transpose to (B,C,H,W), overwriting winner slots last
    {
        int threads = 256;
        int blocks = (ncell4 + threads - 1) / threads;
        bev_gather<<<blocks, threads, 0, stream>>>(feats, out, ncell4);
    }
}